// Round 5
// baseline (194.666 us; speedup 1.0000x reference)
//
#include <hip/hip_runtime.h>
#include <hip/hip_bf16.h>
#include <math.h>

// Problem constants
#define SEQ   2048
#define HID   1024
#define NH    16
#define NKV   4
#define DH    64
#define GQ    (NH / NKV)
#define NQKV  1536          // fused QKV output width
#define LQKV  1536          // row stride of fused QKV output
#define KT    32            // attention key-tile
#define QB    32            // queries per block (2 x 16 per wave)

typedef __attribute__((ext_vector_type(8))) short bf16x8;
typedef __attribute__((ext_vector_type(4))) float f32x4;
typedef unsigned short u16;
typedef unsigned int u32;

__device__ __forceinline__ u16 f2bf(float f) {
    union { float f; unsigned u; } x; x.f = f;
    unsigned r = x.u + 0x7fffu + ((x.u >> 16) & 1u);   // RNE
    return (u16)(r >> 16);
}
__device__ __forceinline__ u32 pk2bf(float lo, float hi) {
    return (u32)f2bf(lo) | ((u32)f2bf(hi) << 16);
}
// async global->LDS, 16B per lane; LDS dest = wave-uniform base + lane*16
__device__ __forceinline__ void load_lds16(const u16* g, u16* l) {
    __builtin_amdgcn_global_load_lds(
        (const __attribute__((address_space(1))) unsigned int*)g,
        (__attribute__((address_space(3))) unsigned int*)l, 16, 0, 0);
}

// ---------------------------------------------------------------------------
// fp32 (K x N) -> bf16 transposed (N x K).  Grid: (N/32, K/32), block 256.
// ---------------------------------------------------------------------------
__global__ __launch_bounds__(256) void transpose_cvt(const float* __restrict__ in,
                                                     u16* __restrict__ out,
                                                     int K, int N) {
    __shared__ float t[32][33];
    const int tx = threadIdx.x & 31;
    const int ty = threadIdx.x >> 5;
    const int n0 = blockIdx.x * 32;
    const int k0 = blockIdx.y * 32;
    #pragma unroll
    for (int i = 0; i < 4; ++i)
        t[ty + i * 8][tx] = in[(size_t)(k0 + ty + i * 8) * N + n0 + tx];
    __syncthreads();
    #pragma unroll
    for (int i = 0; i < 4; ++i)
        out[(size_t)(n0 + ty + i * 8) * K + k0 + tx] = f2bf(t[tx][ty + i * 8]);
}

// ---------------------------------------------------------------------------
// fp32 -> bf16 row-major copy (4 elems/thread).
// ---------------------------------------------------------------------------
__global__ __launch_bounds__(256) void cvt_bf16(const float* __restrict__ in,
                                                u16* __restrict__ out) {
    const int i = blockIdx.x * 256 + threadIdx.x;
    const float4 v = ((const float4*)in)[i];
    ushort4 o;
    o.x = f2bf(v.x); o.y = f2bf(v.y); o.z = f2bf(v.z); o.w = f2bf(v.w);
    ((ushort4*)out)[i] = o;
}

// ---------------------------------------------------------------------------
// bf16 MFMA GEMM, B-transposed: C[M,N](fp32) = A[M,K](bf16) @ Bt[N,K]^T(bf16)
// BM=128, BN=64, BK=32. 256 threads = 4 waves. Grid: (N/64, M/128).
// Staging via global_load_lds width=16 (async, no VGPR round-trip).
// ---------------------------------------------------------------------------
__global__ __launch_bounds__(256) void gemm_bt(const u16* __restrict__ A,
                                               const u16* __restrict__ Bt,
                                               float* __restrict__ C,
                                               int K, int ldc) {
    __shared__ u16 As[128 * 32];
    __shared__ u16 Bs[64 * 32];

    const int tid  = threadIdx.x;
    const int lane = tid & 63;
    const int w    = tid >> 6;
    const int m0   = blockIdx.y * 128;
    const int n0   = blockIdx.x * 64;

    const int mfrag = lane & 15;
    const int kfrag = (lane >> 4) * 8;
    const int mb    = w * 32;

    // staging addresses: wave w stages A rows m0+32w..+31 (2 chunks of 16),
    // B rows n0+16w..+15 (1 chunk). lane covers row base+lane/4, 16B at (lane&3)*16.
    const int arow = w * 32 + (lane >> 2);
    const int acol = (lane & 3) * 8;
    const u16* gA = A  + (size_t)(m0 + arow) * K + acol;
    const u16* gB = Bt + (size_t)(n0 + w * 16 + (lane >> 2)) * K + acol;

    f32x4 acc[2][4];
    #pragma unroll
    for (int mt = 0; mt < 2; ++mt)
        #pragma unroll
        for (int nt = 0; nt < 4; ++nt)
            acc[mt][nt] = (f32x4){0.f, 0.f, 0.f, 0.f};

    for (int k0 = 0; k0 < K; k0 += 32) {
        __syncthreads();
        load_lds16(gA + k0,            &As[(w * 32) * 32]);
        load_lds16(gA + 16 * K + k0,   &As[(w * 32 + 16) * 32]);
        load_lds16(gB + k0,            &Bs[(w * 16) * 32]);
        __syncthreads();   // drains vmcnt + lgkmcnt

        bf16x8 af[2], bfr[4];
        af[0] = *(const bf16x8*)&As[(mb + mfrag) * 32 + kfrag];
        af[1] = *(const bf16x8*)&As[(mb + 16 + mfrag) * 32 + kfrag];
        #pragma unroll
        for (int nt = 0; nt < 4; ++nt)
            bfr[nt] = *(const bf16x8*)&Bs[(nt * 16 + mfrag) * 32 + kfrag];

        #pragma unroll
        for (int mt = 0; mt < 2; ++mt)
            #pragma unroll
            for (int nt = 0; nt < 4; ++nt)
                acc[mt][nt] = __builtin_amdgcn_mfma_f32_16x16x32_bf16(af[mt], bfr[nt], acc[mt][nt], 0, 0, 0);
    }

    const int col   = lane & 15;
    const int rbase = (lane >> 4) * 4;
    #pragma unroll
    for (int mt = 0; mt < 2; ++mt)
        #pragma unroll
        for (int nt = 0; nt < 4; ++nt)
            #pragma unroll
            for (int rg = 0; rg < 4; ++rg)
                C[(size_t)(m0 + mb + mt * 16 + rbase + rg) * ldc + n0 + nt * 16 + col] = acc[mt][nt][rg];
}

// ---------------------------------------------------------------------------
// Post-QKV processing: RoPE on Q and K, emit bf16 buffers:
//   Qb [s][h*64+d] (pre-scaled by 1/8), Kb [kh][s][d], VTg [kh][d][s].
// ---------------------------------------------------------------------------
__global__ __launch_bounds__(256) void postprocess(const float* __restrict__ QKV,
                                                   u16* __restrict__ Qb,
                                                   u16* __restrict__ Kb,
                                                   u16* __restrict__ VTg) {
    const int s   = blockIdx.x;
    const int tid = threadIdx.x;
    const float* row = QKV + (size_t)s * LQKV;
    const float ln_scale = 9.210340371976184f / 32.0f;   // ln(10000)/32

    #pragma unroll
    for (int it = 0; it < 2; ++it) {
        const int p = tid + it * 256;
        const int j = p & 31;
        const float inv_freq = __expf(-(float)((2 * j) & 31) * ln_scale);
        float sn, cs;
        __sincosf((float)s * inv_freq, &sn, &cs);
        const float xe = row[2 * p], xo = row[2 * p + 1];
        Qb[(size_t)s * HID + 2 * p]     = f2bf((xe * cs - xo * sn) * 0.125f);
        Qb[(size_t)s * HID + 2 * p + 1] = f2bf((xe * sn + xo * cs) * 0.125f);
    }
    if (tid < 128) {
        const int p  = tid;
        const int j  = p & 31;
        const int kh = p >> 5;
        const int d  = (2 * p) & 63;
        const float inv_freq = __expf(-(float)((2 * j) & 31) * ln_scale);
        float sn, cs;
        __sincosf((float)s * inv_freq, &sn, &cs);
        const float xe = row[1024 + 2 * p], xo = row[1024 + 2 * p + 1];
        u16* kr = Kb + ((size_t)kh * SEQ + s) * DH;
        kr[d]     = f2bf(xe * cs - xo * sn);
        kr[d + 1] = f2bf(xe * sn + xo * cs);
    }
    {
        const int c = tid;
        const int kh = c >> 6, d = c & 63;
        VTg[((size_t)kh * DH + d) * SEQ + s] = f2bf(row[1280 + c]);
    }
}

// ---------------------------------------------------------------------------
// MFMA flash attention v2: S^T formulation.
//   S^T = K·Q^T  (A=K-frag, B=Q-frag: C-layout row=key, col=query)
//   O^T = V^T·P^T (A=V^T-frag, B=P^T-frag)
// Block = 4 waves = 4 q-heads of kv-head kh, QB=32 queries (2 q-tiles/wave).
// Grid (SEQ/QB=64, NKV) reversed. P^T round-trips per-wave LDS as packed u32
// (2-way bank aliasing = free), no cross-wave sync. l is per-column -> one
// cross-quad reduce at the end; normalization is lane-uniform.
// ---------------------------------------------------------------------------
__global__ __launch_bounds__(256) void attn_kernel(const u16* __restrict__ Qb,
                                                   const u16* __restrict__ Kb,
                                                   const u16* __restrict__ VTg,
                                                   u16* __restrict__ At) {
    __shared__ u16 Kst[32 * 72];        // [key][d], stride 72
    __shared__ u16 VTst[64 * 40];       // [d][key], stride 40
    __shared__ u16 Pst[4][32 * 40];     // per-wave [g*16+q][key], stride 40

    const int tid  = threadIdx.x;
    const int lane = tid & 63;
    const int w    = tid >> 6;
    const int c    = lane & 15;
    const int quad = lane >> 4;
    const int kh   = blockIdx.y;
    const int h    = kh * GQ + w;
    const int qt   = (int)(gridDim.x - 1) - (int)blockIdx.x;  // heavy first
    const int q0   = qt * QB;

    // Q B-fragments (loop-invariant): B[k=d'=quad*8+j][n=q=c] for 2 q-tiles x 2 k-steps
    bf16x8 qf[2][2];
    #pragma unroll
    for (int g = 0; g < 2; ++g)
        #pragma unroll
        for (int ks = 0; ks < 2; ++ks)
            qf[g][ks] = *(const bf16x8*)&Qb[(size_t)(q0 + g * 16 + c) * HID + h * DH + ks * 32 + quad * 8];

    f32x4 accO[4][2];
    #pragma unroll
    for (int nt = 0; nt < 4; ++nt)
        #pragma unroll
        for (int g = 0; g < 2; ++g)
            accO[nt][g] = (f32x4){0.f, 0.f, 0.f, 0.f};
    float l[2] = {0.f, 0.f};

    const int ntiles = q0 / KT + 1;
    for (int t = 0; t < ntiles; ++t) {
        const int kt0 = t * KT;
        __syncthreads();
        {   // stage K tile: 32 rows x 128B, 8 threads/row
            const int r = tid >> 3, off = (tid & 7) * 8;
            *(uint4*)&Kst[r * 72 + off] =
                *(const uint4*)&Kb[((size_t)kh * SEQ + kt0 + r) * DH + off];
        }
        {   // stage V^T tile: 64 rows x 64B, 4 threads/row
            const int r = tid >> 2, off = (tid & 3) * 8;
            *(uint4*)&VTst[r * 40 + off] =
                *(const uint4*)&VTg[((size_t)kh * DH + r) * SEQ + kt0 + off];
        }
        __syncthreads();

        // ---- S^T = K·Q^T: 2 key-tiles x 2 q-tiles, K-dim = 64 (2 steps)
        f32x4 accS[2][2];
        #pragma unroll
        for (int nS = 0; nS < 2; ++nS)
            #pragma unroll
            for (int g = 0; g < 2; ++g)
                accS[nS][g] = (f32x4){0.f, 0.f, 0.f, 0.f};
        #pragma unroll
        for (int nS = 0; nS < 2; ++nS)
            #pragma unroll
            for (int ks = 0; ks < 2; ++ks) {
                const bf16x8 kf = *(const bf16x8*)&Kst[(nS * 16 + c) * 72 + ks * 32 + quad * 8];
                #pragma unroll
                for (int g = 0; g < 2; ++g)
                    accS[nS][g] = __builtin_amdgcn_mfma_f32_16x16x32_bf16(kf, qf[g][ks], accS[nS][g], 0, 0, 0);
            }

        // ---- mask + exp (row=key=kt0+nS*16+quad*4+rg, col=q=q0+g*16+c);
        //      accumulate per-column l; write P^T as packed u32 pairs
        #pragma unroll
        for (int g = 0; g < 2; ++g) {
            const int q = q0 + g * 16 + c;
            #pragma unroll
            for (int nS = 0; nS < 2; ++nS) {
                const int key = kt0 + nS * 16 + quad * 4;
                float p0 = (key + 0 <= q) ? __expf(accS[nS][g][0]) : 0.f;
                float p1 = (key + 1 <= q) ? __expf(accS[nS][g][1]) : 0.f;
                float p2 = (key + 2 <= q) ? __expf(accS[nS][g][2]) : 0.f;
                float p3 = (key + 3 <= q) ? __expf(accS[nS][g][3]) : 0.f;
                l[g] += (p0 + p1) + (p2 + p3);
                u32* dst = (u32*)&Pst[w][(g * 16 + c) * 40 + nS * 16 + quad * 4];
                dst[0] = pk2bf(p0, p1);
                dst[1] = pk2bf(p2, p3);
            }
        }
        __threadfence_block();   // same-wave LDS write->read ordering

        // ---- O^T += V^T·P^T: 4 d-tiles x 2 q-tiles, K-dim = 32 keys
        #pragma unroll
        for (int nt = 0; nt < 4; ++nt) {
            const bf16x8 vf = *(const bf16x8*)&VTst[(nt * 16 + c) * 40 + quad * 8];
            #pragma unroll
            for (int g = 0; g < 2; ++g) {
                const bf16x8 pf = *(const bf16x8*)&Pst[w][(g * 16 + c) * 40 + quad * 8];
                accO[nt][g] = __builtin_amdgcn_mfma_f32_16x16x32_bf16(vf, pf, accO[nt][g], 0, 0, 0);
            }
        }
    }

    // ---- reduce l across the 4 quads (same column c), normalize, store
    #pragma unroll
    for (int g = 0; g < 2; ++g) {
        float ls = l[g];
        ls += __shfl_xor(ls, 16);
        ls += __shfl_xor(ls, 32);
        const float linv = 1.0f / ls;
        const size_t qrow = (size_t)(q0 + g * 16 + c) * HID + h * DH;
        #pragma unroll
        for (int nt = 0; nt < 4; ++nt) {
            ushort4 o;
            o.x = f2bf(accO[nt][g][0] * linv);
            o.y = f2bf(accO[nt][g][1] * linv);
            o.z = f2bf(accO[nt][g][2] * linv);
            o.w = f2bf(accO[nt][g][3] * linv);
            *(ushort4*)&At[qrow + nt * 16 + quad * 4] = o;
        }
    }
}

// ---------------------------------------------------------------------------
extern "C" void kernel_launch(void* const* d_in, const int* in_sizes, int n_in,
                              void* d_out, int out_size, void* d_ws, size_t ws_size,
                              hipStream_t stream) {
    const float* X  = (const float*)d_in[0];
    const float* Wq = (const float*)d_in[1];
    const float* Wk = (const float*)d_in[2];
    const float* Wv = (const float*)d_in[3];
    const float* Wo = (const float*)d_in[4];
    float* out = (float*)d_out;

    // workspace layout (u16 elements unless noted)
    u16* Wt   = (u16*)d_ws;                       // 1536 x 1024
    u16* WoT  = Wt + (size_t)NQKV * HID;          // 1024 x 1024
    u16* Xb   = WoT + (size_t)HID * HID;          // 2048 x 1024
    u16* At   = Xb + (size_t)SEQ * HID;           // 2048 x 1024
    u16* Qb   = At + (size_t)SEQ * HID;           // 2048 x 1024
    u16* Kb   = Qb + (size_t)SEQ * HID;           // 4 x 2048 x 64
    u16* VTg  = Kb + (size_t)NKV * SEQ * DH;      // 4 x 64 x 2048
    float* QKVc = (float*)(VTg + (size_t)NKV * DH * SEQ);  // 2048 x 1536 fp32

    dim3 blk(256);

    transpose_cvt<<<dim3(HID / 32, HID / 32), blk, 0, stream>>>(Wq, Wt, HID, HID);
    transpose_cvt<<<dim3((NKV * DH) / 32, HID / 32), blk, 0, stream>>>(Wk, Wt + (size_t)HID * HID, HID, NKV * DH);
    transpose_cvt<<<dim3((NKV * DH) / 32, HID / 32), blk, 0, stream>>>(Wv, Wt + (size_t)(HID + NKV * DH) * HID, HID, NKV * DH);
    transpose_cvt<<<dim3(HID / 32, HID / 32), blk, 0, stream>>>(Wo, WoT, HID, HID);

    cvt_bf16<<<(SEQ * HID / 4) / 256, blk, 0, stream>>>(X, Xb);

    gemm_bt<<<dim3(NQKV / 64, SEQ / 128), blk, 0, stream>>>(Xb, Wt, QKVc, HID, LQKV);

    postprocess<<<SEQ, blk, 0, stream>>>(QKVc, Qb, Kb, VTg);

    attn_kernel<<<dim3(SEQ / QB, NKV), blk, 0, stream>>>(Qb, Kb, VTg, At);

    gemm_bt<<<dim3(HID / 64, SEQ / 128), blk, 0, stream>>>(At, WoT, out, HID, HID);
}

// Round 7
// 169.990 us; speedup vs baseline: 1.1452x; 1.1452x over previous
//
#include <hip/hip_runtime.h>
#include <hip/hip_bf16.h>
#include <math.h>

// Problem constants
#define SEQ   2048
#define HID   1024
#define NH    16
#define NKV   4
#define DH    64
#define GQ    (NH / NKV)
#define NQKV  1536          // fused QKV output width
#define LQKV  1536          // row stride of fused QKV output
#define KT    64            // attention key-tile (16 MFMA per barrier pair)
#define CH    1024          // split-K chunk of keys
#define PSTR  72            // LDS row stride (u16) — conflict-free phases

typedef __attribute__((ext_vector_type(8))) short bf16x8;
typedef __attribute__((ext_vector_type(4))) float f32x4;
typedef unsigned short u16;
typedef unsigned int u32;

__device__ __forceinline__ u16 f2bf(float f) {
    union { float f; unsigned u; } x; x.f = f;
    unsigned r = x.u + 0x7fffu + ((x.u >> 16) & 1u);   // RNE
    return (u16)(r >> 16);
}
__device__ __forceinline__ u32 pk2bf(float lo, float hi) {
    return (u32)f2bf(lo) | ((u32)f2bf(hi) << 16);
}
// async global->LDS, 16B per lane; LDS dest = wave-uniform base + lane*16
__device__ __forceinline__ void load_lds16(const u16* g, u16* l) {
    __builtin_amdgcn_global_load_lds(
        (const __attribute__((address_space(1))) unsigned int*)g,
        (__attribute__((address_space(3))) unsigned int*)l, 16, 0, 0);
}

// ---------------------------------------------------------------------------
// All four weight transposes in one launch. z selects the matrix.
// in: fp32 (1024 x N) -> out: bf16 (N x 1024). Grid (32, 32, 4), block 256.
// ---------------------------------------------------------------------------
__global__ __launch_bounds__(256) void prep_weights(const float* __restrict__ Wq,
                                                    const float* __restrict__ Wk,
                                                    const float* __restrict__ Wv,
                                                    const float* __restrict__ Wo,
                                                    u16* __restrict__ Wt,
                                                    u16* __restrict__ WoT) {
    const int z = blockIdx.z;
    const float* in; u16* out; int N;
    if (z == 0)      { in = Wq; out = Wt;                           N = HID; }
    else if (z == 1) { in = Wk; out = Wt + (size_t)HID * HID;       N = 256; }
    else if (z == 2) { in = Wv; out = Wt + (size_t)(HID + 256) * HID; N = 256; }
    else             { in = Wo; out = WoT;                          N = HID; }

    const int n0 = blockIdx.x * 32;
    if (n0 >= N) return;
    const int k0 = blockIdx.y * 32;

    __shared__ float t[32][33];
    const int tx = threadIdx.x & 31;
    const int ty = threadIdx.x >> 5;
    #pragma unroll
    for (int i = 0; i < 4; ++i)
        t[ty + i * 8][tx] = in[(size_t)(k0 + ty + i * 8) * N + n0 + tx];
    __syncthreads();
    #pragma unroll
    for (int i = 0; i < 4; ++i)
        out[(size_t)(n0 + ty + i * 8) * HID + k0 + tx] = f2bf(t[tx][ty + i * 8]);
}

// ---------------------------------------------------------------------------
// fp32 -> bf16 row-major copy (4 elems/thread).
// ---------------------------------------------------------------------------
__global__ __launch_bounds__(256) void cvt_bf16(const float* __restrict__ in,
                                                u16* __restrict__ out) {
    const int i = blockIdx.x * 256 + threadIdx.x;
    const float4 v = ((const float4*)in)[i];
    ushort4 o;
    o.x = f2bf(v.x); o.y = f2bf(v.y); o.z = f2bf(v.z); o.w = f2bf(v.w);
    ((ushort4*)out)[i] = o;
}

// ---------------------------------------------------------------------------
// bf16 MFMA GEMM, B-transposed: C[M,N](fp32) = A[M,K](bf16) @ Bt[N,K]^T(bf16)
// BM=128, BN=64, BK=32. 256 threads = 4 waves. Grid: (N/64, M/128).
// Staging via global_load_lds width=16 (async, no VGPR round-trip).
// ---------------------------------------------------------------------------
__global__ __launch_bounds__(256) void gemm_bt(const u16* __restrict__ A,
                                               const u16* __restrict__ Bt,
                                               float* __restrict__ C,
                                               int K, int ldc) {
    __shared__ u16 As[128 * 32];
    __shared__ u16 Bs[64 * 32];

    const int tid  = threadIdx.x;
    const int lane = tid & 63;
    const int w    = tid >> 6;
    const int m0   = blockIdx.y * 128;
    const int n0   = blockIdx.x * 64;

    const int mfrag = lane & 15;
    const int kfrag = (lane >> 4) * 8;
    const int mb    = w * 32;

    const int arow = w * 32 + (lane >> 2);
    const int acol = (lane & 3) * 8;
    const u16* gA = A  + (size_t)(m0 + arow) * K + acol;
    const u16* gB = Bt + (size_t)(n0 + w * 16 + (lane >> 2)) * K + acol;

    f32x4 acc[2][4];
    #pragma unroll
    for (int mt = 0; mt < 2; ++mt)
        #pragma unroll
        for (int nt = 0; nt < 4; ++nt)
            acc[mt][nt] = (f32x4){0.f, 0.f, 0.f, 0.f};

    for (int k0 = 0; k0 < K; k0 += 32) {
        __syncthreads();
        load_lds16(gA + k0,            &As[(w * 32) * 32]);
        load_lds16(gA + 16 * K + k0,   &As[(w * 32 + 16) * 32]);
        load_lds16(gB + k0,            &Bs[(w * 16) * 32]);
        __syncthreads();

        bf16x8 af[2], bfr[4];
        af[0] = *(const bf16x8*)&As[(mb + mfrag) * 32 + kfrag];
        af[1] = *(const bf16x8*)&As[(mb + 16 + mfrag) * 32 + kfrag];
        #pragma unroll
        for (int nt = 0; nt < 4; ++nt)
            bfr[nt] = *(const bf16x8*)&Bs[(nt * 16 + mfrag) * 32 + kfrag];

        #pragma unroll
        for (int mt = 0; mt < 2; ++mt)
            #pragma unroll
            for (int nt = 0; nt < 4; ++nt)
                acc[mt][nt] = __builtin_amdgcn_mfma_f32_16x16x32_bf16(af[mt], bfr[nt], acc[mt][nt], 0, 0, 0);
    }

    const int col   = lane & 15;
    const int rbase = (lane >> 4) * 4;
    #pragma unroll
    for (int mt = 0; mt < 2; ++mt)
        #pragma unroll
        for (int nt = 0; nt < 4; ++nt)
            #pragma unroll
            for (int rg = 0; rg < 4; ++rg)
                C[(size_t)(m0 + mb + mt * 16 + rbase + rg) * ldc + n0 + nt * 16 + col] = acc[mt][nt][rg];
}

// ---------------------------------------------------------------------------
// Post-QKV processing: RoPE on Q and K, emit bf16 buffers:
//   Qb [s][h*64+d] (pre-scaled by 1/8), Kb [kh][s][d], VTg [kh][d][s].
// ---------------------------------------------------------------------------
__global__ __launch_bounds__(256) void postprocess(const float* __restrict__ QKV,
                                                   u16* __restrict__ Qb,
                                                   u16* __restrict__ Kb,
                                                   u16* __restrict__ VTg) {
    const int s   = blockIdx.x;
    const int tid = threadIdx.x;
    const float* row = QKV + (size_t)s * LQKV;
    const float ln_scale = 9.210340371976184f / 32.0f;   // ln(10000)/32

    #pragma unroll
    for (int it = 0; it < 2; ++it) {
        const int p = tid + it * 256;
        const int j = p & 31;
        const float inv_freq = __expf(-(float)((2 * j) & 31) * ln_scale);
        float sn, cs;
        __sincosf((float)s * inv_freq, &sn, &cs);
        const float xe = row[2 * p], xo = row[2 * p + 1];
        Qb[(size_t)s * HID + 2 * p]     = f2bf((xe * cs - xo * sn) * 0.125f);
        Qb[(size_t)s * HID + 2 * p + 1] = f2bf((xe * sn + xo * cs) * 0.125f);
    }
    if (tid < 128) {
        const int p  = tid;
        const int j  = p & 31;
        const int kh = p >> 5;
        const int d  = (2 * p) & 63;
        const float inv_freq = __expf(-(float)((2 * j) & 31) * ln_scale);
        float sn, cs;
        __sincosf((float)s * inv_freq, &sn, &cs);
        const float xe = row[1024 + 2 * p], xo = row[1024 + 2 * p + 1];
        u16* kr = Kb + ((size_t)kh * SEQ + s) * DH;
        kr[d]     = f2bf(xe * cs - xo * sn);
        kr[d + 1] = f2bf(xe * sn + xo * cs);
    }
    {
        const int c = tid;
        const int kh = c >> 6, d = c & 63;
        VTg[((size_t)kh * DH + d) * SEQ + s] = f2bf(row[1280 + c]);
    }
}

// ---------------------------------------------------------------------------
// MFMA flash attention v3: S^T formulation + split-K over key chunks.
//   S^T = K·Q^T ; O^T = V^T·P^T  (no-max exp -> chunk partials sum linearly)
// Block = 4 waves = 4 q-heads of kv-head kh, 16 queries, one CH=1024 key
// chunk. Grid (SEQ/16=128 reversed, NKV, 2). Emits UNNORMALIZED partial
// O (fp32) and l per chunk; attn_reduce merges.
// ---------------------------------------------------------------------------
__global__ __launch_bounds__(256) void attn_kernel(const u16* __restrict__ Qb,
                                                   const u16* __restrict__ Kb,
                                                   const u16* __restrict__ VTg,
                                                   float* __restrict__ Opart,
                                                   float* __restrict__ lpart) {
    __shared__ u16 Kst[64 * PSTR];      // [key][d]
    __shared__ u16 VTst[64 * PSTR];     // [d][key]
    __shared__ u16 Pst[4][16 * PSTR];   // per-wave [q][key]

    const int tid  = threadIdx.x;
    const int lane = tid & 63;
    const int w    = tid >> 6;
    const int c    = lane & 15;
    const int quad = lane >> 4;
    const int kh   = blockIdx.y;
    const int z    = blockIdx.z;
    const int qt   = (SEQ / 16 - 1) - (int)blockIdx.x;   // heavy first
    const int q0   = qt * 16;
    const int h    = kh * GQ + w;

    const int kstart = z * CH;
    const int klim   = q0 + 16;
    const int kend   = (klim < kstart + CH) ? klim : (kstart + CH);
    if (kstart >= kend) return;                // empty chunk (z=1, q0<1024)
    const int ntiles = (kend - kstart + KT - 1) / KT;

    // Q B-fragments (loop-invariant): B[k=d=ks*32+quad*8+j][n=q=c]
    bf16x8 qf[2];
    #pragma unroll
    for (int ks = 0; ks < 2; ++ks)
        qf[ks] = *(const bf16x8*)&Qb[(size_t)(q0 + c) * HID + h * DH + ks * 32 + quad * 8];

    f32x4 accO[4];
    #pragma unroll
    for (int nt = 0; nt < 4; ++nt) accO[nt] = (f32x4){0.f, 0.f, 0.f, 0.f};
    float l = 0.f;

    for (int t = 0; t < ntiles; ++t) {
        const int kt0 = kstart + t * KT;
        __syncthreads();
        {   // stage K tile (64 keys x 128B) and V^T tile (64 d x 128B)
            const int r = tid >> 3, off = (tid & 7) * 8;
            const u16* kg = &Kb[((size_t)kh * SEQ + kt0 + r) * DH + off];
            *(uint4*)&Kst[r * PSTR + off]        = *(const uint4*)kg;
            *(uint4*)&Kst[(r + 32) * PSTR + off] = *(const uint4*)(kg + 32 * DH);
            const u16* vg = &VTg[((size_t)kh * DH + r) * SEQ + kt0 + off];
            *(uint4*)&VTst[r * PSTR + off]        = *(const uint4*)vg;
            *(uint4*)&VTst[(r + 32) * PSTR + off] = *(const uint4*)(vg + 32 * SEQ);
        }
        __syncthreads();

        // ---- S^T = K·Q^T: 4 key-frags x 2 k-steps
        f32x4 accS[4];
        #pragma unroll
        for (int nS = 0; nS < 4; ++nS) accS[nS] = (f32x4){0.f, 0.f, 0.f, 0.f};
        #pragma unroll
        for (int nS = 0; nS < 4; ++nS)
            #pragma unroll
            for (int ks = 0; ks < 2; ++ks) {
                const bf16x8 kf = *(const bf16x8*)&Kst[(nS * 16 + c) * PSTR + ks * 32 + quad * 8];
                accS[nS] = __builtin_amdgcn_mfma_f32_16x16x32_bf16(kf, qf[ks], accS[nS], 0, 0, 0);
            }

        // ---- mask + exp (row=key, col=q=q0+c); per-column l; packed P^T
        const int q = q0 + c;
        #pragma unroll
        for (int nS = 0; nS < 4; ++nS) {
            const int key = kt0 + nS * 16 + quad * 4;
            const float p0 = (key + 0 <= q) ? __expf(accS[nS][0]) : 0.f;
            const float p1 = (key + 1 <= q) ? __expf(accS[nS][1]) : 0.f;
            const float p2 = (key + 2 <= q) ? __expf(accS[nS][2]) : 0.f;
            const float p3 = (key + 3 <= q) ? __expf(accS[nS][3]) : 0.f;
            l += (p0 + p1) + (p2 + p3);
            u32* dst = (u32*)&Pst[w][c * PSTR + nS * 16 + quad * 4];
            dst[0] = pk2bf(p0, p1);
            dst[1] = pk2bf(p2, p3);
        }
        __threadfence_block();   // same-wave LDS write->read ordering

        // ---- O^T += V^T·P^T: 4 d-frags x 2 key-steps
        #pragma unroll
        for (int ks2 = 0; ks2 < 2; ++ks2) {
            const bf16x8 pf = *(const bf16x8*)&Pst[w][c * PSTR + ks2 * 32 + quad * 8];
            #pragma unroll
            for (int nt = 0; nt < 4; ++nt) {
                const bf16x8 vf = *(const bf16x8*)&VTst[(nt * 16 + c) * PSTR + ks2 * 32 + quad * 8];
                accO[nt] = __builtin_amdgcn_mfma_f32_16x16x32_bf16(vf, pf, accO[nt], 0, 0, 0);
            }
        }
    }

    // ---- per-column l: reduce across quads; store partials (unnormalized)
    l += __shfl_xor(l, 16);
    l += __shfl_xor(l, 32);
    if (quad == 0)
        lpart[((size_t)z * SEQ + q0 + c) * NH + h] = l;

    float* Op = Opart + ((size_t)z * SEQ + q0 + c) * HID + h * DH;
    #pragma unroll
    for (int nt = 0; nt < 4; ++nt)
        *(f32x4*)&Op[nt * 16 + quad * 4] = accO[nt];
}

// ---------------------------------------------------------------------------
// Merge split-K partials: At = (O0 + [q>=CH]·O1) / (l0 + [q>=CH]·l1), bf16.
// Grid: SEQ*HID/4/256 blocks. Chunk-1 entries for q<CH are never read.
// ---------------------------------------------------------------------------
__global__ __launch_bounds__(256) void attn_reduce(const float* __restrict__ Opart,
                                                   const float* __restrict__ lpart,
                                                   u16* __restrict__ At) {
    const int idx = blockIdx.x * 256 + threadIdx.x;   // float4 index
    const int q  = idx >> 8;                          // 256 float4 per row
    const int h  = (idx & 255) >> 4;                  // 16 float4 per head
    float4 o = ((const float4*)Opart)[idx];
    float  l = lpart[q * NH + h];
    if (q >= CH) {
        const float4 o1 = ((const float4*)Opart)[idx + SEQ * HID / 4];
        o.x += o1.x; o.y += o1.y; o.z += o1.z; o.w += o1.w;
        l += lpart[SEQ * NH + q * NH + h];
    }
    const float inv = 1.0f / l;
    ushort4 r;
    r.x = f2bf(o.x * inv); r.y = f2bf(o.y * inv);
    r.z = f2bf(o.z * inv); r.w = f2bf(o.w * inv);
    ((ushort4*)At)[idx] = r;
}

// ---------------------------------------------------------------------------
extern "C" void kernel_launch(void* const* d_in, const int* in_sizes, int n_in,
                              void* d_out, int out_size, void* d_ws, size_t ws_size,
                              hipStream_t stream) {
    const float* X  = (const float*)d_in[0];
    const float* Wq = (const float*)d_in[1];
    const float* Wk = (const float*)d_in[2];
    const float* Wv = (const float*)d_in[3];
    const float* Wo = (const float*)d_in[4];
    float* out = (float*)d_out;

    // workspace layout
    u16* Wt     = (u16*)d_ws;                        // 1536 x 1024 bf16
    u16* WoT    = Wt + (size_t)NQKV * HID;           // 1024 x 1024
    u16* Xb     = WoT + (size_t)HID * HID;           // 2048 x 1024
    u16* At     = Xb + (size_t)SEQ * HID;            // 2048 x 1024
    u16* Qb     = At + (size_t)SEQ * HID;            // 2048 x 1024
    u16* Kb     = Qb + (size_t)SEQ * HID;            // 4 x 2048 x 64
    u16* VTg    = Kb + (size_t)NKV * SEQ * DH;       // 4 x 64 x 2048
    float* QKVc = (float*)(VTg + (size_t)NKV * DH * SEQ);   // 2048 x 1536 fp32
    float* Opart = QKVc + (size_t)SEQ * LQKV;        // 2 x 2048 x 1024 fp32
    float* lpart = Opart + (size_t)2 * SEQ * HID;    // 2 x 2048 x 16 fp32

    dim3 blk(256);

    prep_weights<<<dim3(32, 32, 4), blk, 0, stream>>>(Wq, Wk, Wv, Wo, Wt, WoT);

    cvt_bf16<<<(SEQ * HID / 4) / 256, blk, 0, stream>>>(X, Xb);

    gemm_bt<<<dim3(NQKV / 64, SEQ / 128), blk, 0, stream>>>(Xb, Wt, QKVc, HID, LQKV);

    postprocess<<<SEQ, blk, 0, stream>>>(QKVc, Qb, Kb, VTg);

    attn_kernel<<<dim3(SEQ / 16, NKV, 2), blk, 0, stream>>>(Qb, Kb, VTg, Opart, lpart);

    attn_reduce<<<(SEQ * HID / 4) / 256, blk, 0, stream>>>(Opart, lpart, At);

    gemm_bt<<<dim3(HID / 64, SEQ / 128), blk, 0, stream>>>(At, WoT, out, HID, HID);
}

// Round 8
// 162.156 us; speedup vs baseline: 1.2005x; 1.0483x over previous
//
#include <hip/hip_runtime.h>
#include <hip/hip_bf16.h>
#include <math.h>

// Problem constants
#define SEQ   2048
#define HID   1024
#define NH    16
#define NKV   4
#define DH    64
#define GQ    (NH / NKV)
#define NQKV  1536          // fused QKV output width
#define LQKV  1536          // row stride of fused QKV output
#define KT    64            // attention key-tile
#define QB    32            // queries per block (2 q-frags per wave)
#define CH    512           // split-K chunk of keys (4 chunks)
#define NCH   (SEQ / CH)    // 4
#define PSTR  72            // LDS row stride (u16)

typedef __attribute__((ext_vector_type(8))) short bf16x8;
typedef __attribute__((ext_vector_type(4))) float f32x4;
typedef unsigned short u16;
typedef unsigned int u32;

__device__ __forceinline__ u16 f2bf(float f) {
    union { float f; unsigned u; } x; x.f = f;
    unsigned r = x.u + 0x7fffu + ((x.u >> 16) & 1u);   // RNE
    return (u16)(r >> 16);
}
__device__ __forceinline__ u32 pk2bf(float lo, float hi) {
    return (u32)f2bf(lo) | ((u32)f2bf(hi) << 16);
}
// async global->LDS, 16B per lane; LDS dest = wave-uniform base + lane*16
__device__ __forceinline__ void load_lds16(const u16* g, u16* l) {
    __builtin_amdgcn_global_load_lds(
        (const __attribute__((address_space(1))) unsigned int*)g,
        (__attribute__((address_space(3))) unsigned int*)l, 16, 0, 0);
}

// ---------------------------------------------------------------------------
// All four weight transposes in one launch. z selects the matrix.
// in: fp32 (1024 x N) -> out: bf16 (N x 1024). Grid (32, 32, 4), block 256.
// ---------------------------------------------------------------------------
__global__ __launch_bounds__(256) void prep_weights(const float* __restrict__ Wq,
                                                    const float* __restrict__ Wk,
                                                    const float* __restrict__ Wv,
                                                    const float* __restrict__ Wo,
                                                    u16* __restrict__ Wt,
                                                    u16* __restrict__ WoT) {
    const int z = blockIdx.z;
    const float* in; u16* out; int N;
    if (z == 0)      { in = Wq; out = Wt;                           N = HID; }
    else if (z == 1) { in = Wk; out = Wt + (size_t)HID * HID;       N = 256; }
    else if (z == 2) { in = Wv; out = Wt + (size_t)(HID + 256) * HID; N = 256; }
    else             { in = Wo; out = WoT;                          N = HID; }

    const int n0 = blockIdx.x * 32;
    if (n0 >= N) return;
    const int k0 = blockIdx.y * 32;

    __shared__ float t[32][33];
    const int tx = threadIdx.x & 31;
    const int ty = threadIdx.x >> 5;
    #pragma unroll
    for (int i = 0; i < 4; ++i)
        t[ty + i * 8][tx] = in[(size_t)(k0 + ty + i * 8) * N + n0 + tx];
    __syncthreads();
    #pragma unroll
    for (int i = 0; i < 4; ++i)
        out[(size_t)(n0 + ty + i * 8) * HID + k0 + tx] = f2bf(t[tx][ty + i * 8]);
}

// ---------------------------------------------------------------------------
// fp32 -> bf16 row-major copy (4 elems/thread).
// ---------------------------------------------------------------------------
__global__ __launch_bounds__(256) void cvt_bf16(const float* __restrict__ in,
                                                u16* __restrict__ out) {
    const int i = blockIdx.x * 256 + threadIdx.x;
    const float4 v = ((const float4*)in)[i];
    ushort4 o;
    o.x = f2bf(v.x); o.y = f2bf(v.y); o.z = f2bf(v.z); o.w = f2bf(v.w);
    ((ushort4*)out)[i] = o;
}

// ---------------------------------------------------------------------------
// bf16 MFMA GEMM, B-transposed: C[M,N](fp32) = A[M,K](bf16) @ Bt[N,K]^T(bf16)
// BM=128, BN=64, BK=32. 256 threads = 4 waves. Grid: (N/64, M/128).
// ---------------------------------------------------------------------------
__global__ __launch_bounds__(256) void gemm_bt(const u16* __restrict__ A,
                                               const u16* __restrict__ Bt,
                                               float* __restrict__ C,
                                               int K, int ldc) {
    __shared__ u16 As[128 * 32];
    __shared__ u16 Bs[64 * 32];

    const int tid  = threadIdx.x;
    const int lane = tid & 63;
    const int w    = tid >> 6;
    const int m0   = blockIdx.y * 128;
    const int n0   = blockIdx.x * 64;

    const int mfrag = lane & 15;
    const int kfrag = (lane >> 4) * 8;
    const int mb    = w * 32;

    const int arow = w * 32 + (lane >> 2);
    const int acol = (lane & 3) * 8;
    const u16* gA = A  + (size_t)(m0 + arow) * K + acol;
    const u16* gB = Bt + (size_t)(n0 + w * 16 + (lane >> 2)) * K + acol;

    f32x4 acc[2][4];
    #pragma unroll
    for (int mt = 0; mt < 2; ++mt)
        #pragma unroll
        for (int nt = 0; nt < 4; ++nt)
            acc[mt][nt] = (f32x4){0.f, 0.f, 0.f, 0.f};

    for (int k0 = 0; k0 < K; k0 += 32) {
        __syncthreads();
        load_lds16(gA + k0,            &As[(w * 32) * 32]);
        load_lds16(gA + 16 * K + k0,   &As[(w * 32 + 16) * 32]);
        load_lds16(gB + k0,            &Bs[(w * 16) * 32]);
        __syncthreads();

        bf16x8 af[2], bfr[4];
        af[0] = *(const bf16x8*)&As[(mb + mfrag) * 32 + kfrag];
        af[1] = *(const bf16x8*)&As[(mb + 16 + mfrag) * 32 + kfrag];
        #pragma unroll
        for (int nt = 0; nt < 4; ++nt)
            bfr[nt] = *(const bf16x8*)&Bs[(nt * 16 + mfrag) * 32 + kfrag];

        #pragma unroll
        for (int mt = 0; mt < 2; ++mt)
            #pragma unroll
            for (int nt = 0; nt < 4; ++nt)
                acc[mt][nt] = __builtin_amdgcn_mfma_f32_16x16x32_bf16(af[mt], bfr[nt], acc[mt][nt], 0, 0, 0);
    }

    const int col   = lane & 15;
    const int rbase = (lane >> 4) * 4;
    #pragma unroll
    for (int mt = 0; mt < 2; ++mt)
        #pragma unroll
        for (int nt = 0; nt < 4; ++nt)
            #pragma unroll
            for (int rg = 0; rg < 4; ++rg)
                C[(size_t)(m0 + mb + mt * 16 + rbase + rg) * ldc + n0 + nt * 16 + col] = acc[mt][nt][rg];
}

// ---------------------------------------------------------------------------
// Post-QKV processing: RoPE on Q and K, emit bf16 buffers:
//   Qb [s][h*64+d] (pre-scaled by 1/8), Kb [kh][s][d], VTg [kh][d][s].
// ---------------------------------------------------------------------------
__global__ __launch_bounds__(256) void postprocess(const float* __restrict__ QKV,
                                                   u16* __restrict__ Qb,
                                                   u16* __restrict__ Kb,
                                                   u16* __restrict__ VTg) {
    const int s   = blockIdx.x;
    const int tid = threadIdx.x;
    const float* row = QKV + (size_t)s * LQKV;
    const float ln_scale = 9.210340371976184f / 32.0f;   // ln(10000)/32

    #pragma unroll
    for (int it = 0; it < 2; ++it) {
        const int p = tid + it * 256;
        const int j = p & 31;
        const float inv_freq = __expf(-(float)((2 * j) & 31) * ln_scale);
        float sn, cs;
        __sincosf((float)s * inv_freq, &sn, &cs);
        const float xe = row[2 * p], xo = row[2 * p + 1];
        Qb[(size_t)s * HID + 2 * p]     = f2bf((xe * cs - xo * sn) * 0.125f);
        Qb[(size_t)s * HID + 2 * p + 1] = f2bf((xe * sn + xo * cs) * 0.125f);
    }
    if (tid < 128) {
        const int p  = tid;
        const int j  = p & 31;
        const int kh = p >> 5;
        const int d  = (2 * p) & 63;
        const float inv_freq = __expf(-(float)((2 * j) & 31) * ln_scale);
        float sn, cs;
        __sincosf((float)s * inv_freq, &sn, &cs);
        const float xe = row[1024 + 2 * p], xo = row[1024 + 2 * p + 1];
        u16* kr = Kb + ((size_t)kh * SEQ + s) * DH;
        kr[d]     = f2bf(xe * cs - xo * sn);
        kr[d + 1] = f2bf(xe * sn + xo * cs);
    }
    {
        const int c = tid;
        const int kh = c >> 6, d = c & 63;
        VTg[((size_t)kh * DH + d) * SEQ + s] = f2bf(row[1280 + c]);
    }
}

// ---------------------------------------------------------------------------
// MFMA flash attention v4: QB=32 queries/block + split-K (CH=512).
//   S^T = K·Q^T ; O^T = V^T·P^T  (no-max exp -> chunk partials sum linearly)
// Block = 4 waves = 4 q-heads of kv-head kh; each wave: 2 q-frags (32 q).
// 32 MFMA per barrier pair. Grid (SEQ/QB=64 reversed, NKV, NCH=4).
// Emits UNNORMALIZED partial O (fp32) + l per chunk; attn_reduce merges.
// ---------------------------------------------------------------------------
__global__ __launch_bounds__(256) void attn_kernel(const u16* __restrict__ Qb,
                                                   const u16* __restrict__ Kb,
                                                   const u16* __restrict__ VTg,
                                                   float* __restrict__ Opart,
                                                   float* __restrict__ lpart) {
    __shared__ u16 Kst[64 * PSTR];      // [key][d]
    __shared__ u16 VTst[64 * PSTR];     // [d][key]
    __shared__ u16 Pst[4][QB * PSTR];   // per-wave [q][key]

    const int tid  = threadIdx.x;
    const int lane = tid & 63;
    const int w    = tid >> 6;
    const int c    = lane & 15;
    const int quad = lane >> 4;
    const int kh   = blockIdx.y;
    const int z    = blockIdx.z;
    const int qt   = (SEQ / QB - 1) - (int)blockIdx.x;   // heavy first
    const int q0   = qt * QB;
    const int h    = kh * GQ + w;

    const int kstart = z * CH;
    const int klim   = q0 + QB;
    if (kstart >= klim) return;                 // empty chunk
    const int kend   = (klim < kstart + CH) ? klim : (kstart + CH);
    const int ntiles = (kend - kstart + KT - 1) / KT;

    // Q B-fragments (loop-invariant): B[k=d=ks*32+quad*8+j][n=q=g*16+c]
    bf16x8 qf[2][2];
    #pragma unroll
    for (int g = 0; g < 2; ++g)
        #pragma unroll
        for (int ks = 0; ks < 2; ++ks)
            qf[g][ks] = *(const bf16x8*)&Qb[(size_t)(q0 + g * 16 + c) * HID + h * DH + ks * 32 + quad * 8];

    f32x4 accO[4][2];
    #pragma unroll
    for (int nt = 0; nt < 4; ++nt)
        #pragma unroll
        for (int g = 0; g < 2; ++g)
            accO[nt][g] = (f32x4){0.f, 0.f, 0.f, 0.f};
    float l[2] = {0.f, 0.f};

    for (int t = 0; t < ntiles; ++t) {
        const int kt0 = kstart + t * KT;
        __syncthreads();
        {   // stage K tile (64 keys x 128B) and V^T tile (64 d x 128B)
            const int r = tid >> 3, off = (tid & 7) * 8;
            const u16* kg = &Kb[((size_t)kh * SEQ + kt0 + r) * DH + off];
            *(uint4*)&Kst[r * PSTR + off]        = *(const uint4*)kg;
            *(uint4*)&Kst[(r + 32) * PSTR + off] = *(const uint4*)(kg + 32 * DH);
            const u16* vg = &VTg[((size_t)kh * DH + r) * SEQ + kt0 + off];
            *(uint4*)&VTst[r * PSTR + off]        = *(const uint4*)vg;
            *(uint4*)&VTst[(r + 32) * PSTR + off] = *(const uint4*)(vg + 32 * SEQ);
        }
        __syncthreads();

        // ---- S^T = K·Q^T: 4 key-frags x 2 k-steps x 2 q-frags
        f32x4 accS[4][2];
        #pragma unroll
        for (int nS = 0; nS < 4; ++nS)
            #pragma unroll
            for (int g = 0; g < 2; ++g)
                accS[nS][g] = (f32x4){0.f, 0.f, 0.f, 0.f};
        #pragma unroll
        for (int nS = 0; nS < 4; ++nS)
            #pragma unroll
            for (int ks = 0; ks < 2; ++ks) {
                const bf16x8 kf = *(const bf16x8*)&Kst[(nS * 16 + c) * PSTR + ks * 32 + quad * 8];
                #pragma unroll
                for (int g = 0; g < 2; ++g)
                    accS[nS][g] = __builtin_amdgcn_mfma_f32_16x16x32_bf16(kf, qf[g][ks], accS[nS][g], 0, 0, 0);
            }

        // ---- mask + exp (row=key, col=q); per-column l; packed P^T
        #pragma unroll
        for (int g = 0; g < 2; ++g) {
            const int q = q0 + g * 16 + c;
            #pragma unroll
            for (int nS = 0; nS < 4; ++nS) {
                const int key = kt0 + nS * 16 + quad * 4;
                const float p0 = (key + 0 <= q) ? __expf(accS[nS][g][0]) : 0.f;
                const float p1 = (key + 1 <= q) ? __expf(accS[nS][g][1]) : 0.f;
                const float p2 = (key + 2 <= q) ? __expf(accS[nS][g][2]) : 0.f;
                const float p3 = (key + 3 <= q) ? __expf(accS[nS][g][3]) : 0.f;
                l[g] += (p0 + p1) + (p2 + p3);
                u32* dst = (u32*)&Pst[w][(g * 16 + c) * PSTR + nS * 16 + quad * 4];
                dst[0] = pk2bf(p0, p1);
                dst[1] = pk2bf(p2, p3);
            }
        }
        __threadfence_block();   // same-wave LDS write->read ordering

        // ---- O^T += V^T·P^T: 4 d-frags x 2 key-steps x 2 q-frags
        #pragma unroll
        for (int ks2 = 0; ks2 < 2; ++ks2) {
            bf16x8 pf[2];
            #pragma unroll
            for (int g = 0; g < 2; ++g)
                pf[g] = *(const bf16x8*)&Pst[w][(g * 16 + c) * PSTR + ks2 * 32 + quad * 8];
            #pragma unroll
            for (int nt = 0; nt < 4; ++nt) {
                const bf16x8 vf = *(const bf16x8*)&VTst[(nt * 16 + c) * PSTR + ks2 * 32 + quad * 8];
                #pragma unroll
                for (int g = 0; g < 2; ++g)
                    accO[nt][g] = __builtin_amdgcn_mfma_f32_16x16x32_bf16(vf, pf[g], accO[nt][g], 0, 0, 0);
            }
        }
    }

    // ---- per-column l: reduce across quads; store partials (unnormalized)
    #pragma unroll
    for (int g = 0; g < 2; ++g) {
        float lg = l[g];
        lg += __shfl_xor(lg, 16);
        lg += __shfl_xor(lg, 32);
        if (quad == 0)
            lpart[((size_t)z * SEQ + q0 + g * 16 + c) * NH + h] = lg;

        float* Op = Opart + ((size_t)z * SEQ + q0 + g * 16 + c) * HID + h * DH;
        #pragma unroll
        for (int nt = 0; nt < 4; ++nt)
            *(f32x4*)&Op[nt * 16 + quad * 4] = accO[nt][g];
    }
}

// ---------------------------------------------------------------------------
// Merge split-K partials: At[q] = sum_z O_z[q] / sum_z l_z[q], bf16.
// Chunk z contributes iff z*CH < (q & ~(QB-1)) + QB.
// ---------------------------------------------------------------------------
__global__ __launch_bounds__(256) void attn_reduce(const float* __restrict__ Opart,
                                                   const float* __restrict__ lpart,
                                                   u16* __restrict__ At) {
    const int idx = blockIdx.x * 256 + threadIdx.x;   // float4 index
    const int q  = idx >> 8;                          // 256 float4 per row
    const int h  = (idx & 255) >> 4;                  // 16 float4 per head
    const int klim = (q & ~(QB - 1)) + QB;
    float4 o = ((const float4*)Opart)[idx];
    float  l = lpart[q * NH + h];
    #pragma unroll
    for (int z = 1; z < NCH; ++z) {
        if (z * CH < klim) {
            const float4 o1 = ((const float4*)Opart)[idx + z * (SEQ * HID / 4)];
            o.x += o1.x; o.y += o1.y; o.z += o1.z; o.w += o1.w;
            l += lpart[(z * SEQ + q) * NH + h];
        }
    }
    const float inv = 1.0f / l;
    ushort4 r;
    r.x = f2bf(o.x * inv); r.y = f2bf(o.y * inv);
    r.z = f2bf(o.z * inv); r.w = f2bf(o.w * inv);
    ((ushort4*)At)[idx] = r;
}

// ---------------------------------------------------------------------------
extern "C" void kernel_launch(void* const* d_in, const int* in_sizes, int n_in,
                              void* d_out, int out_size, void* d_ws, size_t ws_size,
                              hipStream_t stream) {
    const float* X  = (const float*)d_in[0];
    const float* Wq = (const float*)d_in[1];
    const float* Wk = (const float*)d_in[2];
    const float* Wv = (const float*)d_in[3];
    const float* Wo = (const float*)d_in[4];
    float* out = (float*)d_out;

    // workspace layout (Opart overlaps dead QKVc to bound footprint ~52 MB)
    u16* Wt     = (u16*)d_ws;                        // 1536 x 1024 bf16
    u16* WoT    = Wt + (size_t)NQKV * HID;           // 1024 x 1024
    u16* Xb     = WoT + (size_t)HID * HID;           // 2048 x 1024
    u16* At     = Xb + (size_t)SEQ * HID;            // 2048 x 1024
    u16* Qb     = At + (size_t)SEQ * HID;            // 2048 x 1024
    u16* Kb     = Qb + (size_t)SEQ * HID;            // 4 x 2048 x 64
    u16* VTg    = Kb + (size_t)NKV * SEQ * DH;       // 4 x 64 x 2048
    float* QKVc = (float*)(VTg + (size_t)NKV * DH * SEQ);   // 2048 x 1536 fp32
    float* Opart = QKVc;                             // reuse: NCH x 2048 x 1024 fp32
    float* lpart = Opart + (size_t)NCH * SEQ * HID;  // NCH x 2048 x 16 fp32

    dim3 blk(256);

    prep_weights<<<dim3(32, 32, 4), blk, 0, stream>>>(Wq, Wk, Wv, Wo, Wt, WoT);

    cvt_bf16<<<(SEQ * HID / 4) / 256, blk, 0, stream>>>(X, Xb);

    gemm_bt<<<dim3(NQKV / 64, SEQ / 128), blk, 0, stream>>>(Xb, Wt, QKVc, HID, LQKV);

    postprocess<<<SEQ, blk, 0, stream>>>(QKVc, Qb, Kb, VTg);

    attn_kernel<<<dim3(SEQ / QB, NKV, NCH), blk, 0, stream>>>(Qb, Kb, VTg, Opart, lpart);

    attn_reduce<<<(SEQ * HID / 4) / 256, blk, 0, stream>>>(Opart, lpart, At);

    gemm_bt<<<dim3(HID / 64, SEQ / 128), blk, 0, stream>>>(At, WoT, out, HID, HID);
}

// Round 9
// 158.638 us; speedup vs baseline: 1.2271x; 1.0222x over previous
//
#include <hip/hip_runtime.h>
#include <hip/hip_bf16.h>
#include <math.h>

// Problem constants
#define SEQ   2048
#define HID   1024
#define NH    16
#define NKV   4
#define DH    64
#define GQ    (NH / NKV)
#define NQKV  1536          // fused QKV output width
#define LQKV  1536          // row stride of fused QKV output
#define KT    64            // attention key-tile
#define QB    32            // queries per block (2 q-frags per wave)
#define CH    512           // split-K chunk of keys (4 chunks)
#define NCH   (SEQ / CH)    // 4
#define PSTR  72            // LDS row stride (u16)

typedef __attribute__((ext_vector_type(8))) short bf16x8;
typedef __attribute__((ext_vector_type(4))) float f32x4;
typedef unsigned short u16;
typedef unsigned int u32;

__device__ __forceinline__ u16 f2bf(float f) {
    union { float f; unsigned u; } x; x.f = f;
    unsigned r = x.u + 0x7fffu + ((x.u >> 16) & 1u);   // RNE
    return (u16)(r >> 16);
}
__device__ __forceinline__ u32 pk2bf(float lo, float hi) {
    return (u32)f2bf(lo) | ((u32)f2bf(hi) << 16);
}
// async global->LDS, 16B per lane; LDS dest = wave-uniform base + lane*16
__device__ __forceinline__ void load_lds16(const u16* g, u16* l) {
    __builtin_amdgcn_global_load_lds(
        (const __attribute__((address_space(1))) unsigned int*)g,
        (__attribute__((address_space(3))) unsigned int*)l, 16, 0, 0);
}

// ---------------------------------------------------------------------------
// Setup: weight transposes (z=0..3) + X fp32->bf16 convert (z=4), one launch.
// Grid (64, 32, 5), block 256.
// ---------------------------------------------------------------------------
__global__ __launch_bounds__(256) void setup(const float* __restrict__ X,
                                             const float* __restrict__ Wq,
                                             const float* __restrict__ Wk,
                                             const float* __restrict__ Wv,
                                             const float* __restrict__ Wo,
                                             u16* __restrict__ Xb,
                                             u16* __restrict__ Wt,
                                             u16* __restrict__ WoT) {
    const int z = blockIdx.z;
    if (z == 4) {
        // X convert: one float4 per thread. 2048 blocks x 256 thr = 524288 f4.
        const int idx = ((int)blockIdx.y * 64 + (int)blockIdx.x) * 256 + threadIdx.x;
        const float4 v = ((const float4*)X)[idx];
        ushort4 o;
        o.x = f2bf(v.x); o.y = f2bf(v.y); o.z = f2bf(v.z); o.w = f2bf(v.w);
        ((ushort4*)Xb)[idx] = o;
        return;
    }
    const float* in; u16* out; int N;
    if (z == 0)      { in = Wq; out = Wt;                             N = HID; }
    else if (z == 1) { in = Wk; out = Wt + (size_t)HID * HID;         N = 256; }
    else if (z == 2) { in = Wv; out = Wt + (size_t)(HID + 256) * HID; N = 256; }
    else             { in = Wo; out = WoT;                            N = HID; }

    const int n0 = blockIdx.x * 32;
    if (n0 >= N) return;
    const int k0 = blockIdx.y * 32;

    __shared__ float t[32][33];
    const int tx = threadIdx.x & 31;
    const int ty = threadIdx.x >> 5;
    #pragma unroll
    for (int i = 0; i < 4; ++i)
        t[ty + i * 8][tx] = in[(size_t)(k0 + ty + i * 8) * N + n0 + tx];
    __syncthreads();
    #pragma unroll
    for (int i = 0; i < 4; ++i)
        out[(size_t)(n0 + ty + i * 8) * HID + k0 + tx] = f2bf(t[tx][ty + i * 8]);
}

// ---------------------------------------------------------------------------
// bf16 MFMA GEMM v2: C[M,N](fp32) = A[M,K](bf16) @ Bt[N,K]^T(bf16).
// BM=128, BN=64, BK=32; 256 thr = 4 waves (wave w: rows w*32..w*32+31).
// Single-barrier double-buffered K-loop: next B-tile (async global->LDS)
// and next A-fragments (direct 16B global loads, no LDS) are issued right
// after the barrier, so their latency overlaps this tile's ds_read+MFMA.
// Grid: (N/64, M/128).
// ---------------------------------------------------------------------------
__global__ __launch_bounds__(256) void gemm_v2(const u16* __restrict__ A,
                                               const u16* __restrict__ Bt,
                                               float* __restrict__ C,
                                               int K, int ldc) {
    __shared__ u16 Bs[2][64 * 32];

    const int tid  = threadIdx.x;
    const int lane = tid & 63;
    const int w    = tid >> 6;
    const int c    = lane & 15;
    const int quad = lane >> 4;
    const int m0   = blockIdx.y * 128;
    const int n0   = blockIdx.x * 64;

    // B staging: wave w stages rows n0+w*16..+15 (1 async issue per iter)
    const u16* gB  = Bt + (size_t)(n0 + w * 16 + (lane >> 2)) * K + (lane & 3) * 8;
    u16* const bdst = (u16*)&Bs[0][0] + (w * 16) * 32;   // +64*32 for buf 1

    // A direct fragments: lane (c,quad) owns rows m0+w*32+{0,16}+c, k-chunk quad*8
    const u16* gA0 = A + (size_t)(m0 + w * 32 + c) * K + quad * 8;
    const u16* gA1 = gA0 + (size_t)16 * K;

    const int T = K / 32;

    f32x4 acc[2][4];
    #pragma unroll
    for (int mt = 0; mt < 2; ++mt)
        #pragma unroll
        for (int nt = 0; nt < 4; ++nt)
            acc[mt][nt] = (f32x4){0.f, 0.f, 0.f, 0.f};

    // prologue: tile 0
    bf16x8 afc[2], afn[2];
    afc[0] = *(const bf16x8*)gA0;
    afc[1] = *(const bf16x8*)gA1;
    load_lds16(gB, bdst);

    for (int t = 0; t < T; ++t) {
        __syncthreads();   // tile t staged; buf[(t+1)&1] free (read out in t-1)
        if (t + 1 < T) {
            load_lds16(gB + (t + 1) * 32, bdst + ((t + 1) & 1) * (64 * 32));
            afn[0] = *(const bf16x8*)(gA0 + (t + 1) * 32);
            afn[1] = *(const bf16x8*)(gA1 + (t + 1) * 32);
        }
        bf16x8 bfr[4];
        #pragma unroll
        for (int nt = 0; nt < 4; ++nt)
            bfr[nt] = *(const bf16x8*)&Bs[t & 1][(nt * 16 + c) * 32 + quad * 8];
        #pragma unroll
        for (int mt = 0; mt < 2; ++mt)
            #pragma unroll
            for (int nt = 0; nt < 4; ++nt)
                acc[mt][nt] = __builtin_amdgcn_mfma_f32_16x16x32_bf16(afc[mt], bfr[nt], acc[mt][nt], 0, 0, 0);
        afc[0] = afn[0];
        afc[1] = afn[1];
    }

    // C/D layout: col = lane&15, row = quad*4 + reg
    #pragma unroll
    for (int mt = 0; mt < 2; ++mt)
        #pragma unroll
        for (int nt = 0; nt < 4; ++nt)
            #pragma unroll
            for (int rg = 0; rg < 4; ++rg)
                C[(size_t)(m0 + w * 32 + mt * 16 + quad * 4 + rg) * ldc + n0 + nt * 16 + c] = acc[mt][nt][rg];
}

// ---------------------------------------------------------------------------
// Post-QKV processing: RoPE on Q and K, emit bf16 buffers:
//   Qb [s][h*64+d] (pre-scaled by 1/8), Kb [kh][s][d], VTg [kh][d][s].
// ---------------------------------------------------------------------------
__global__ __launch_bounds__(256) void postprocess(const float* __restrict__ QKV,
                                                   u16* __restrict__ Qb,
                                                   u16* __restrict__ Kb,
                                                   u16* __restrict__ VTg) {
    const int s   = blockIdx.x;
    const int tid = threadIdx.x;
    const float* row = QKV + (size_t)s * LQKV;
    const float ln_scale = 9.210340371976184f / 32.0f;   // ln(10000)/32

    #pragma unroll
    for (int it = 0; it < 2; ++it) {
        const int p = tid + it * 256;
        const int j = p & 31;
        const float inv_freq = __expf(-(float)((2 * j) & 31) * ln_scale);
        float sn, cs;
        __sincosf((float)s * inv_freq, &sn, &cs);
        const float xe = row[2 * p], xo = row[2 * p + 1];
        Qb[(size_t)s * HID + 2 * p]     = f2bf((xe * cs - xo * sn) * 0.125f);
        Qb[(size_t)s * HID + 2 * p + 1] = f2bf((xe * sn + xo * cs) * 0.125f);
    }
    if (tid < 128) {
        const int p  = tid;
        const int j  = p & 31;
        const int kh = p >> 5;
        const int d  = (2 * p) & 63;
        const float inv_freq = __expf(-(float)((2 * j) & 31) * ln_scale);
        float sn, cs;
        __sincosf((float)s * inv_freq, &sn, &cs);
        const float xe = row[1024 + 2 * p], xo = row[1024 + 2 * p + 1];
        u16* kr = Kb + ((size_t)kh * SEQ + s) * DH;
        kr[d]     = f2bf(xe * cs - xo * sn);
        kr[d + 1] = f2bf(xe * sn + xo * cs);
    }
    {
        const int c = tid;
        const int kh = c >> 6, d = c & 63;
        VTg[((size_t)kh * DH + d) * SEQ + s] = f2bf(row[1280 + c]);
    }
}

// ---------------------------------------------------------------------------
// MFMA flash attention v4 (unchanged from round 8): QB=32 + split-K CH=512.
//   S^T = K·Q^T ; O^T = V^T·P^T  (no-max exp -> chunk partials sum linearly)
// Grid (SEQ/QB=64 reversed, NKV, NCH=4). Unnormalized partials + l.
// ---------------------------------------------------------------------------
__global__ __launch_bounds__(256) void attn_kernel(const u16* __restrict__ Qb,
                                                   const u16* __restrict__ Kb,
                                                   const u16* __restrict__ VTg,
                                                   float* __restrict__ Opart,
                                                   float* __restrict__ lpart) {
    __shared__ u16 Kst[64 * PSTR];      // [key][d]
    __shared__ u16 VTst[64 * PSTR];     // [d][key]
    __shared__ u16 Pst[4][QB * PSTR];   // per-wave [q][key]

    const int tid  = threadIdx.x;
    const int lane = tid & 63;
    const int w    = tid >> 6;
    const int c    = lane & 15;
    const int quad = lane >> 4;
    const int kh   = blockIdx.y;
    const int z    = blockIdx.z;
    const int qt   = (SEQ / QB - 1) - (int)blockIdx.x;   // heavy first
    const int q0   = qt * QB;
    const int h    = kh * GQ + w;

    const int kstart = z * CH;
    const int klim   = q0 + QB;
    if (kstart >= klim) return;                 // empty chunk
    const int kend   = (klim < kstart + CH) ? klim : (kstart + CH);
    const int ntiles = (kend - kstart + KT - 1) / KT;

    bf16x8 qf[2][2];
    #pragma unroll
    for (int g = 0; g < 2; ++g)
        #pragma unroll
        for (int ks = 0; ks < 2; ++ks)
            qf[g][ks] = *(const bf16x8*)&Qb[(size_t)(q0 + g * 16 + c) * HID + h * DH + ks * 32 + quad * 8];

    f32x4 accO[4][2];
    #pragma unroll
    for (int nt = 0; nt < 4; ++nt)
        #pragma unroll
        for (int g = 0; g < 2; ++g)
            accO[nt][g] = (f32x4){0.f, 0.f, 0.f, 0.f};
    float l[2] = {0.f, 0.f};

    for (int t = 0; t < ntiles; ++t) {
        const int kt0 = kstart + t * KT;
        __syncthreads();
        {
            const int r = tid >> 3, off = (tid & 7) * 8;
            const u16* kg = &Kb[((size_t)kh * SEQ + kt0 + r) * DH + off];
            *(uint4*)&Kst[r * PSTR + off]        = *(const uint4*)kg;
            *(uint4*)&Kst[(r + 32) * PSTR + off] = *(const uint4*)(kg + 32 * DH);
            const u16* vg = &VTg[((size_t)kh * DH + r) * SEQ + kt0 + off];
            *(uint4*)&VTst[r * PSTR + off]        = *(const uint4*)vg;
            *(uint4*)&VTst[(r + 32) * PSTR + off] = *(const uint4*)(vg + 32 * SEQ);
        }
        __syncthreads();

        f32x4 accS[4][2];
        #pragma unroll
        for (int nS = 0; nS < 4; ++nS)
            #pragma unroll
            for (int g = 0; g < 2; ++g)
                accS[nS][g] = (f32x4){0.f, 0.f, 0.f, 0.f};
        #pragma unroll
        for (int nS = 0; nS < 4; ++nS)
            #pragma unroll
            for (int ks = 0; ks < 2; ++ks) {
                const bf16x8 kf = *(const bf16x8*)&Kst[(nS * 16 + c) * PSTR + ks * 32 + quad * 8];
                #pragma unroll
                for (int g = 0; g < 2; ++g)
                    accS[nS][g] = __builtin_amdgcn_mfma_f32_16x16x32_bf16(kf, qf[g][ks], accS[nS][g], 0, 0, 0);
            }

        #pragma unroll
        for (int g = 0; g < 2; ++g) {
            const int q = q0 + g * 16 + c;
            #pragma unroll
            for (int nS = 0; nS < 4; ++nS) {
                const int key = kt0 + nS * 16 + quad * 4;
                const float p0 = (key + 0 <= q) ? __expf(accS[nS][g][0]) : 0.f;
                const float p1 = (key + 1 <= q) ? __expf(accS[nS][g][1]) : 0.f;
                const float p2 = (key + 2 <= q) ? __expf(accS[nS][g][2]) : 0.f;
                const float p3 = (key + 3 <= q) ? __expf(accS[nS][g][3]) : 0.f;
                l[g] += (p0 + p1) + (p2 + p3);
                u32* dst = (u32*)&Pst[w][(g * 16 + c) * PSTR + nS * 16 + quad * 4];
                dst[0] = pk2bf(p0, p1);
                dst[1] = pk2bf(p2, p3);
            }
        }
        __threadfence_block();

        #pragma unroll
        for (int ks2 = 0; ks2 < 2; ++ks2) {
            bf16x8 pf[2];
            #pragma unroll
            for (int g = 0; g < 2; ++g)
                pf[g] = *(const bf16x8*)&Pst[w][(g * 16 + c) * PSTR + ks2 * 32 + quad * 8];
            #pragma unroll
            for (int nt = 0; nt < 4; ++nt) {
                const bf16x8 vf = *(const bf16x8*)&VTst[(nt * 16 + c) * PSTR + ks2 * 32 + quad * 8];
                #pragma unroll
                for (int g = 0; g < 2; ++g)
                    accO[nt][g] = __builtin_amdgcn_mfma_f32_16x16x32_bf16(vf, pf[g], accO[nt][g], 0, 0, 0);
            }
        }
    }

    #pragma unroll
    for (int g = 0; g < 2; ++g) {
        float lg = l[g];
        lg += __shfl_xor(lg, 16);
        lg += __shfl_xor(lg, 32);
        if (quad == 0)
            lpart[((size_t)z * SEQ + q0 + g * 16 + c) * NH + h] = lg;

        float* Op = Opart + ((size_t)z * SEQ + q0 + g * 16 + c) * HID + h * DH;
        #pragma unroll
        for (int nt = 0; nt < 4; ++nt)
            *(f32x4*)&Op[nt * 16 + quad * 4] = accO[nt][g];
    }
}

// ---------------------------------------------------------------------------
// Merge split-K partials: At[q] = sum_z O_z[q] / sum_z l_z[q], bf16.
// ---------------------------------------------------------------------------
__global__ __launch_bounds__(256) void attn_reduce(const float* __restrict__ Opart,
                                                   const float* __restrict__ lpart,
                                                   u16* __restrict__ At) {
    const int idx = blockIdx.x * 256 + threadIdx.x;   // float4 index
    const int q  = idx >> 8;
    const int h  = (idx & 255) >> 4;
    const int klim = (q & ~(QB - 1)) + QB;
    float4 o = ((const float4*)Opart)[idx];
    float  l = lpart[q * NH + h];
    #pragma unroll
    for (int z = 1; z < NCH; ++z) {
        if (z * CH < klim) {
            const float4 o1 = ((const float4*)Opart)[idx + z * (SEQ * HID / 4)];
            o.x += o1.x; o.y += o1.y; o.z += o1.z; o.w += o1.w;
            l += lpart[(z * SEQ + q) * NH + h];
        }
    }
    const float inv = 1.0f / l;
    ushort4 r;
    r.x = f2bf(o.x * inv); r.y = f2bf(o.y * inv);
    r.z = f2bf(o.z * inv); r.w = f2bf(o.w * inv);
    ((ushort4*)At)[idx] = r;
}

// ---------------------------------------------------------------------------
extern "C" void kernel_launch(void* const* d_in, const int* in_sizes, int n_in,
                              void* d_out, int out_size, void* d_ws, size_t ws_size,
                              hipStream_t stream) {
    const float* X  = (const float*)d_in[0];
    const float* Wq = (const float*)d_in[1];
    const float* Wk = (const float*)d_in[2];
    const float* Wv = (const float*)d_in[3];
    const float* Wo = (const float*)d_in[4];
    float* out = (float*)d_out;

    // workspace layout (Opart overlaps dead QKVc to bound footprint)
    u16* Wt     = (u16*)d_ws;                        // 1536 x 1024 bf16
    u16* WoT    = Wt + (size_t)NQKV * HID;           // 1024 x 1024
    u16* Xb     = WoT + (size_t)HID * HID;           // 2048 x 1024
    u16* At     = Xb + (size_t)SEQ * HID;            // 2048 x 1024
    u16* Qb     = At + (size_t)SEQ * HID;            // 2048 x 1024
    u16* Kb     = Qb + (size_t)SEQ * HID;            // 4 x 2048 x 64
    u16* VTg    = Kb + (size_t)NKV * SEQ * DH;       // 4 x 64 x 2048
    float* QKVc = (float*)(VTg + (size_t)NKV * DH * SEQ);   // 2048 x 1536 fp32
    float* Opart = QKVc;                             // reuse: NCH x 2048 x 1024 fp32
    float* lpart = Opart + (size_t)NCH * SEQ * HID;  // NCH x 2048 x 16 fp32

    dim3 blk(256);

    setup<<<dim3(64, 32, 5), blk, 0, stream>>>(X, Wq, Wk, Wv, Wo, Xb, Wt, WoT);

    gemm_v2<<<dim3(NQKV / 64, SEQ / 128), blk, 0, stream>>>(Xb, Wt, QKVc, HID, LQKV);

    postprocess<<<SEQ, blk, 0, stream>>>(QKVc, Qb, Kb, VTg);

    attn_kernel<<<dim3(SEQ / QB, NKV, NCH), blk, 0, stream>>>(Qb, Kb, VTg, Opart, lpart);

    attn_reduce<<<(SEQ * HID / 4) / 256, blk, 0, stream>>>(Opart, lpart, At);

    gemm_v2<<<dim3(HID / 64, SEQ / 128), blk, 0, stream>>>(At, WoT, out, HID, HID);
}